// Round 4
// baseline (1487.478 us; speedup 1.0000x reference)
//
#include <hip/hip_runtime.h>
#include <cstdint>
#include <cstddef>

// ---------------- constants ----------------
#define MROWS   4096      // B*T
#define TSEQ    2048
#define DMODEL  1024
#define NHEAD   16
#define FFN     4096
#define NVOCAB  32000
#define NLAYER  4

typedef float  f32x4  __attribute__((ext_vector_type(4)));
typedef __bf16 bf16x8 __attribute__((ext_vector_type(8)));

__device__ __forceinline__ unsigned short f2bf(float f) {
    unsigned u = __builtin_bit_cast(unsigned, f);
    u += 0x7fffu + ((u >> 16) & 1u);
    return (unsigned short)(u >> 16);
}
__device__ __forceinline__ float bf2f(unsigned short u) {
    return __builtin_bit_cast(float, (unsigned)u << 16);
}

__device__ __forceinline__ float gelu_exact(float v) {
    return 0.5f * v * (1.0f + erff(v * 0.7071067811865476f));
}

// ---------------- embedding ----------------
__global__ __launch_bounds__(256) void embed_kernel(const int* __restrict__ idx,
                                                    const float* __restrict__ tok,
                                                    const float* __restrict__ pos,
                                                    float* __restrict__ x) {
    int row = blockIdx.x, tid = threadIdx.x;
    int token = idx[row];
    int t = row & (TSEQ - 1);
    float4 a = ((const float4*)(tok + (size_t)token * DMODEL))[tid];
    float4 p = ((const float4*)(pos + (size_t)t * DMODEL))[tid];
    a.x += p.x; a.y += p.y; a.z += p.z; a.w += p.w;
    ((float4*)(x + (size_t)row * DMODEL))[tid] = a;
}

// ---------------- LayerNorm fp32 in -> bf16 out ----------------
__global__ __launch_bounds__(256) void ln_kernel(const float* __restrict__ x,
                                                 const float* __restrict__ g,
                                                 const float* __restrict__ b,
                                                 unsigned short* __restrict__ out) {
    int row = blockIdx.x, tid = threadIdx.x;
    float4 v = ((const float4*)(x + (size_t)row * DMODEL))[tid];
    float s1 = v.x + v.y + v.z + v.w;
    float s2 = v.x * v.x + v.y * v.y + v.z * v.z + v.w * v.w;
    for (int s = 32; s; s >>= 1) { s1 += __shfl_xor(s1, s); s2 += __shfl_xor(s2, s); }
    __shared__ float red[8];
    int lane = tid & 63, w = tid >> 6;
    if (lane == 0) { red[w] = s1; red[4 + w] = s2; }
    __syncthreads();
    s1 = red[0] + red[1] + red[2] + red[3];
    s2 = red[4] + red[5] + red[6] + red[7];
    float mean = s1 * (1.0f / DMODEL);
    float var  = s2 * (1.0f / DMODEL) - mean * mean;
    float rs   = rsqrtf(var + 1e-5f);
    float4 gv = ((const float4*)g)[tid];
    float4 bv = ((const float4*)b)[tid];
    size_t o = (size_t)row * DMODEL + tid * 4;
    out[o + 0] = f2bf((v.x - mean) * rs * gv.x + bv.x);
    out[o + 1] = f2bf((v.y - mean) * rs * gv.y + bv.y);
    out[o + 2] = f2bf((v.z - mean) * rs * gv.z + bv.z);
    out[o + 3] = f2bf((v.w - mean) * rs * gv.w + bv.w);
}

// ---------------- fast transpose + fp32->bf16: W[K][N](ldW) -> WT[N][K] ----------------
__global__ __launch_bounds__(256) void transpose_bf16(const float* __restrict__ W,
                                                      unsigned short* __restrict__ WT,
                                                      int K, int ldW) {
    __shared__ float tile[64][65];
    int n0 = blockIdx.x * 64, k0 = blockIdx.y * 64;
    int tid = threadIdx.x;
    int lr4 = tid & 15;
    int rw  = tid >> 4;
#pragma unroll
    for (int p = 0; p < 4; ++p) {
        int k = rw + p * 16;
        float4 v = *(const float4*)(W + (size_t)(k0 + k) * ldW + n0 + lr4 * 4);
        tile[k][lr4 * 4 + 0] = v.x;
        tile[k][lr4 * 4 + 1] = v.y;
        tile[k][lr4 * 4 + 2] = v.z;
        tile[k][lr4 * 4 + 3] = v.w;
    }
    __syncthreads();
    int kc = tid & 15;
    int nr = tid >> 4;
#pragma unroll
    for (int p = 0; p < 4; ++p) {
        int n = nr + p * 16;
        ushort4 o;
        o.x = f2bf(tile[kc * 4 + 0][n]);
        o.y = f2bf(tile[kc * 4 + 1][n]);
        o.z = f2bf(tile[kc * 4 + 2][n]);
        o.w = f2bf(tile[kc * 4 + 3][n]);
        *(ushort4*)(WT + (size_t)(n0 + n) * K + k0 + kc * 4) = o;
    }
}

// fused QKV transpose: z selects Wq/Wk/Wv, writes into 3-stacked WT
__global__ __launch_bounds__(256) void transpose_qkv(const float* __restrict__ Wq,
                                                     const float* __restrict__ Wk,
                                                     const float* __restrict__ Wv,
                                                     unsigned short* __restrict__ WT) {
    __shared__ float tile[64][65];
    const float* W = (blockIdx.z == 0) ? Wq : (blockIdx.z == 1) ? Wk : Wv;
    unsigned short* dst = WT + (size_t)blockIdx.z * DMODEL * DMODEL;
    int n0 = blockIdx.x * 64, k0 = blockIdx.y * 64;
    int tid = threadIdx.x;
    int lr4 = tid & 15, rw = tid >> 4;
#pragma unroll
    for (int p = 0; p < 4; ++p) {
        int k = rw + p * 16;
        float4 v = *(const float4*)(W + (size_t)(k0 + k) * DMODEL + n0 + lr4 * 4);
        tile[k][lr4 * 4 + 0] = v.x;
        tile[k][lr4 * 4 + 1] = v.y;
        tile[k][lr4 * 4 + 2] = v.z;
        tile[k][lr4 * 4 + 3] = v.w;
    }
    __syncthreads();
    int kc = tid & 15, nr = tid >> 4;
#pragma unroll
    for (int p = 0; p < 4; ++p) {
        int n = nr + p * 16;
        ushort4 o;
        o.x = f2bf(tile[kc * 4 + 0][n]);
        o.y = f2bf(tile[kc * 4 + 1][n]);
        o.z = f2bf(tile[kc * 4 + 2][n]);
        o.w = f2bf(tile[kc * 4 + 3][n]);
        *(ushort4*)(dst + (size_t)(n0 + n) * DMODEL + k0 + kc * 4) = o;
    }
}

// ---------------- pack fused QKV bias for all layers ----------------
__global__ __launch_bounds__(256) void pack_qkv_bias(const float* __restrict__ bq,
                                                     const float* __restrict__ bk,
                                                     const float* __restrict__ bv,
                                                     float* __restrict__ dst) {
    int i = blockIdx.x * 256 + threadIdx.x;
    int l = i / 3072, c = i % 3072;
    float v = (c < 1024) ? bq[l * 1024 + c]
            : (c < 2048) ? bk[l * 1024 + c - 1024]
                         : bv[l * 1024 + c - 2048];
    dst[i] = v;
}

// ---------------- band attention (width-3), bf16 qkv in ----------------
__global__ __launch_bounds__(256) void attn_kernel(const unsigned short* __restrict__ qkv,
                                                   unsigned short* __restrict__ y) {
    int wid  = (blockIdx.x * 256 + threadIdx.x) >> 6;
    int lane = threadIdx.x & 63;
    int h = wid & (NHEAD - 1);
    int row = wid >> 4;
    int t = row & (TSEQ - 1);
    const unsigned short* base = qkv + (size_t)row * 3072 + h * 64;
    float qd = bf2f(base[lane]);
    float d0 = qd * bf2f(base[1024 + lane]);
    float d1 = (t >= 1) ? qd * bf2f(base[1024 - 3072 + lane]) : 0.0f;
    float d2 = (t >= 2) ? qd * bf2f(base[1024 - 6144 + lane]) : 0.0f;
    for (int s = 32; s; s >>= 1) {
        d0 += __shfl_xor(d0, s); d1 += __shfl_xor(d1, s); d2 += __shfl_xor(d2, s);
    }
    d0 *= 0.125f; d1 *= 0.125f; d2 *= 0.125f;
    float m = d0;
    if (t >= 1) m = fmaxf(m, d1);
    if (t >= 2) m = fmaxf(m, d2);
    float p0 = expf(d0 - m);
    float p1 = (t >= 1) ? expf(d1 - m) : 0.0f;
    float p2 = (t >= 2) ? expf(d2 - m) : 0.0f;
    float den = p0 + p1 + p2;
    float v0 = bf2f(base[2048 + lane]);
    float v1 = (t >= 1) ? bf2f(base[2048 - 3072 + lane]) : 0.0f;
    float v2 = (t >= 2) ? bf2f(base[2048 - 6144 + lane]) : 0.0f;
    float yv = (p0 * v0 + p1 * v1 + p2 * v2) / den;
    y[(size_t)row * DMODEL + h * 64 + lane] = f2bf(yv);
}

// ======================================================================
// 256x256x64 GEMM, 8 waves, counted-vmcnt 4-phase schedule (T1+T2+T3/T4+T5)
// LDS: per buffer, per operand: 2 K-half regions of 16 KiB.
//   Within a region: line = row>>1 (128 B), slot = (row&1)*4 | (cl ^ (line&3)),
//   cl = k-chunk (16 B) within the K-half. Bank-balanced (8 lanes / 4-bank grp).
// Per K-tile: 4 phases {kh x m-half}; each phase issues ONE half-stage (2 loads)
// for tile t+1; waits are vmcnt(4) at kh boundaries only (never 0 mid-loop).
// ======================================================================
__device__ __forceinline__ void stage_kh(const unsigned short* __restrict__ g,
                                         unsigned short* region, int K, int kh, int tid) {
#pragma unroll
    for (int i = 0; i < 2; ++i) {
        int pc = i * 512 + tid;
        int line = pc >> 3, slot = pc & 7;
        int r  = line * 2 + (slot >> 2);
        int cl = (slot & 3) ^ (line & 3);
        __builtin_amdgcn_global_load_lds(
            (const __attribute__((address_space(1))) void*)(g + (size_t)r * K + kh * 32 + cl * 8),
            (__attribute__((address_space(3))) void*)(region + (size_t)pc * 8), 16, 0, 0);
    }
}

template <int EPI>
__global__ __launch_bounds__(512, 2) void gemm256(const unsigned short* __restrict__ A,
                                                  const unsigned short* __restrict__ BT,
                                                  const float* __restrict__ bias,
                                                  const float* __restrict__ res,
                                                  float* __restrict__ outF,
                                                  unsigned short* __restrict__ outB,
                                                  int M, int N, int K, int ldc) {
    __shared__ unsigned short As[2][2][8192];   // [buf][kh][region]
    __shared__ unsigned short Bs[2][2][8192];
    const int tid = threadIdx.x;
    const int lane = tid & 63, wid = tid >> 6;
    const int wr = wid >> 2, wc = wid & 3;       // 2 x 4 waves; wave tile 128x64
    const int lr = lane & 15, kq = lane >> 4;

    // bijective XCD swizzle (m204)
    const int nbn = N >> 8;
    const int nwg = gridDim.x;
    int orig = blockIdx.x;
    int q8 = nwg >> 3, r8 = nwg & 7;
    int xcd = orig & 7, lin = orig >> 3;
    int wg = (xcd < r8 ? xcd * (q8 + 1) : r8 * (q8 + 1) + (xcd - r8) * q8) + lin;
    int bm = wg / nbn, bn = wg % nbn;

    const unsigned short* Ab = A + (size_t)bm * 256 * K;
    const unsigned short* Bb = BT + (size_t)bn * 256 * K;

    // per-lane LDS read offset (ushort units) within a kh-region:
    // addr = (fb/2 + (lr>>1))*64 + slot*8  with slot lane-constant
    const int slot = ((lane & 1) << 2) | (kq ^ ((lr >> 1) & 3));
    const int laneOff = ((lr >> 1) << 6) + slot * 8;

    f32x4 acc[8][4] = {};
    const int nt = K >> 6;

    // prologue: tile 0, issue order A0,B0,A1,B1 (matches steady state)
    stage_kh(Ab, &As[0][0][0], K, 0, tid);
    stage_kh(Bb, &Bs[0][0][0], K, 0, tid);
    stage_kh(Ab, &As[0][1][0], K, 1, tid);
    stage_kh(Bb, &Bs[0][1][0], K, 1, tid);

    for (int t = 0; t < nt; ++t) {
        const int buf = t & 1;
        const bool pf = (t + 1) < nt;
        const unsigned short* gA = Ab + (size_t)(t + 1) * 64;
        const unsigned short* gB = Bb + (size_t)(t + 1) * 64;

#pragma unroll
        for (int kh = 0; kh < 2; ++kh) {
            // ---- phase (kh, qm=0) ----
            if (kh == 0 || pf) asm volatile("s_waitcnt vmcnt(4)" ::: "memory");
            else               asm volatile("s_waitcnt vmcnt(0)" ::: "memory");
            __builtin_amdgcn_s_barrier();
            if (pf) stage_kh(gA, &As[buf ^ 1][kh][0], K, kh, tid);

            const unsigned short* rA = &As[buf][kh][0];
            const unsigned short* rB = &Bs[buf][kh][0];
            bf16x8 bfrag[4];
#pragma unroll
            for (int n = 0; n < 4; ++n)
                bfrag[n] = *(const bf16x8*)(rB + wc * 2048 + n * 512 + laneOff);
            bf16x8 afrag[4];
#pragma unroll
            for (int j = 0; j < 4; ++j)
                afrag[j] = *(const bf16x8*)(rA + wr * 4096 + j * 512 + laneOff);
            __builtin_amdgcn_s_setprio(1);
#pragma unroll
            for (int j = 0; j < 4; ++j)
#pragma unroll
                for (int n = 0; n < 4; ++n)
                    acc[j][n] = __builtin_amdgcn_mfma_f32_16x16x32_bf16(afrag[j], bfrag[n], acc[j][n], 0, 0, 0);
            __builtin_amdgcn_s_setprio(0);

            // ---- phase (kh, qm=1) ----
            __builtin_amdgcn_s_barrier();
            if (pf) stage_kh(gB, &Bs[buf ^ 1][kh][0], K, kh, tid);
#pragma unroll
            for (int j = 0; j < 4; ++j)
                afrag[j] = *(const bf16x8*)(rA + wr * 4096 + (4 + j) * 512 + laneOff);
            __builtin_amdgcn_s_setprio(1);
#pragma unroll
            for (int j = 0; j < 4; ++j)
#pragma unroll
                for (int n = 0; n < 4; ++n)
                    acc[4 + j][n] = __builtin_amdgcn_mfma_f32_16x16x32_bf16(afrag[j], bfrag[n], acc[4 + j][n], 0, 0, 0);
            __builtin_amdgcn_s_setprio(0);
        }
    }

    // epilogue
    const int row0 = bm * 256 + wr * 128;
    const int col0 = bn * 256 + wc * 64;
#pragma unroll
    for (int m = 0; m < 8; ++m) {
#pragma unroll
        for (int n = 0; n < 4; ++n) {
            int col = col0 + n * 16 + lr;
            int rbase = row0 + m * 16 + kq * 4;
            float bb = bias ? bias[col] : 0.0f;
#pragma unroll
            for (int j = 0; j < 4; ++j) {
                size_t off = (size_t)(rbase + j) * ldc + col;
                float v = acc[m][n][j] + bb;
                if (EPI == 1) v += res[off];
                if (EPI == 2)      outB[off] = f2bf(gelu_exact(v));
                else if (EPI == 3) outB[off] = f2bf(v);
                else               outF[off] = v;
            }
        }
    }
}

// ======================================================================
// 128x128x64, 8-wave, TRIPLE-buffered counted-vmcnt GEMM (for N=1024)
// ======================================================================
__device__ __forceinline__ void stage128(const unsigned short* __restrict__ g,
                                         unsigned short* s, int K, int tid) {
#pragma unroll
    for (int i = 0; i < 2; ++i) {
        int t2 = tid + i * 512;
        int row = t2 >> 3;
        int col = ((t2 & 7) ^ (row & 7)) * 8;
        __builtin_amdgcn_global_load_lds(
            (const __attribute__((address_space(1))) void*)(g + (size_t)row * K + col),
            (__attribute__((address_space(3))) void*)(s + (size_t)t2 * 8), 16, 0, 0);
    }
}

template <int EPI>
__global__ __launch_bounds__(512, 2) void gemm128(const unsigned short* __restrict__ A,
                                                  const unsigned short* __restrict__ BT,
                                                  const float* __restrict__ bias,
                                                  const float* __restrict__ res,
                                                  float* __restrict__ outF,
                                                  unsigned short* __restrict__ outB,
                                                  int M, int N, int K, int ldc) {
    __shared__ unsigned short As[3][128 * 64];
    __shared__ unsigned short Bs[3][128 * 64];
    const int tid = threadIdx.x;
    const int lane = tid & 63, wid = tid >> 6;
    const int wr = wid >> 2, wc = wid & 3;
    const int lr = lane & 15, kq = lane >> 4;

    const int nbn = N >> 7;
    const int nwg = gridDim.x;
    int orig = blockIdx.x;
    int q8 = nwg >> 3, r8 = nwg & 7;
    int xcd = orig & 7, lin = orig >> 3;
    int wg = (xcd < r8 ? xcd * (q8 + 1) : r8 * (q8 + 1) + (xcd - r8) * q8) + lin;
    int bm = wg / nbn, bn = wg % nbn;

    const unsigned short* Ab = A + (size_t)bm * 128 * K;
    const unsigned short* Bb = BT + (size_t)bn * 128 * K;

    const int aBase = (wr * 64 + lr) * 64;
    const int bBase = (wc * 32 + lr) * 64;
    const int c0 = (kq ^ (lr & 7)) * 8;
    const int c1 = ((4 + kq) ^ (lr & 7)) * 8;

    f32x4 acc[4][2] = {};
    const int nt = K >> 6;

    stage128(Ab,      &As[0][0], K, tid);
    stage128(Bb,      &Bs[0][0], K, tid);
    stage128(Ab + 64, &As[1][0], K, tid);
    stage128(Bb + 64, &Bs[1][0], K, tid);
    asm volatile("s_waitcnt vmcnt(4)" ::: "memory");
    __builtin_amdgcn_s_barrier();

    for (int t = 0; t < nt; ++t) {
        const unsigned short* sA = &As[t % 3][0];
        const unsigned short* sB = &Bs[t % 3][0];
        const bool pf = (t + 2) < nt;
        unsigned short* dA = &As[(t + 2) % 3][0];
        unsigned short* dB = &Bs[(t + 2) % 3][0];
        const unsigned short* gA = Ab + (size_t)(t + 2) * 64;
        const unsigned short* gB = Bb + (size_t)(t + 2) * 64;

        bf16x8 bfr[2][2];
#pragma unroll
        for (int n = 0; n < 2; ++n) {
            bfr[n][0] = *reinterpret_cast<const bf16x8*>(sB + bBase + n * 16 * 64 + c0);
            bfr[n][1] = *reinterpret_cast<const bf16x8*>(sB + bBase + n * 16 * 64 + c1);
        }
#pragma unroll
        for (int p = 0; p < 2; ++p) {
            bf16x8 af[2][2];
#pragma unroll
            for (int jm = 0; jm < 2; ++jm) {
                const int ro = aBase + ((p * 2 + jm) * 16) * 64;
                af[jm][0] = *reinterpret_cast<const bf16x8*>(sA + ro + c0);
                af[jm][1] = *reinterpret_cast<const bf16x8*>(sA + ro + c1);
            }
            if (pf && p == 0) stage128(gA, dA, K, tid);
            if (pf && p == 1) stage128(gB, dB, K, tid);
            __builtin_amdgcn_s_barrier();
            __builtin_amdgcn_s_setprio(1);
#pragma unroll
            for (int jm = 0; jm < 2; ++jm)
#pragma unroll
                for (int n = 0; n < 2; ++n) {
                    acc[p * 2 + jm][n] = __builtin_amdgcn_mfma_f32_16x16x32_bf16(af[jm][0], bfr[n][0], acc[p * 2 + jm][n], 0, 0, 0);
                    acc[p * 2 + jm][n] = __builtin_amdgcn_mfma_f32_16x16x32_bf16(af[jm][1], bfr[n][1], acc[p * 2 + jm][n], 0, 0, 0);
                }
            __builtin_amdgcn_s_setprio(0);
        }
        if (t + 1 < nt) {
            if (pf) asm volatile("s_waitcnt vmcnt(4)" ::: "memory");
            else    asm volatile("s_waitcnt vmcnt(0)" ::: "memory");
            __builtin_amdgcn_s_barrier();
        }
    }

    const int row0 = bm * 128 + wr * 64;
    const int col0 = bn * 128 + wc * 32;
#pragma unroll
    for (int m = 0; m < 4; ++m) {
#pragma unroll
        for (int n = 0; n < 2; ++n) {
            int col = col0 + n * 16 + lr;
            int rbase = row0 + m * 16 + kq * 4;
            float bb = bias ? bias[col] : 0.0f;
#pragma unroll
            for (int j = 0; j < 4; ++j) {
                size_t off = (size_t)(rbase + j) * ldc + col;
                float v = acc[m][n][j] + bb;
                if (EPI == 1) v += res[off];
                if (EPI == 2)      outB[off] = f2bf(gelu_exact(v));
                else if (EPI == 3) outB[off] = f2bf(v);
                else               outF[off] = v;
            }
        }
    }
}

// ---------------- host launch ----------------
extern "C" void kernel_launch(void* const* d_in, const int* in_sizes, int n_in,
                              void* d_out, int out_size, void* d_ws, size_t ws_size,
                              hipStream_t stream) {
    const int*   idx  = (const int*)d_in[0];
    const float* tok  = (const float*)d_in[1];
    const float* pos  = (const float*)d_in[2];
    const float* Wq   = (const float*)d_in[3];
    const float* bq   = (const float*)d_in[4];
    const float* Wk   = (const float*)d_in[5];
    const float* bk   = (const float*)d_in[6];
    const float* Wv   = (const float*)d_in[7];
    const float* bv   = (const float*)d_in[8];
    const float* Wo   = (const float*)d_in[9];
    const float* bo   = (const float*)d_in[10];
    const float* ln1g = (const float*)d_in[11];
    const float* ln1b = (const float*)d_in[12];
    const float* W1   = (const float*)d_in[13];
    const float* b1   = (const float*)d_in[14];
    const float* W2   = (const float*)d_in[15];
    const float* b2   = (const float*)d_in[16];
    const float* ln2g = (const float*)d_in[17];
    const float* ln2b = (const float*)d_in[18];
    const float* lnfg = (const float*)d_in[19];
    const float* lnfb = (const float*)d_in[20];
    const float* lmW  = (const float*)d_in[21];

    const bool bigws = ws_size >= (92ull << 20);

    char* ws = (char*)d_ws;
    unsigned short* wbuf;   // rotating weight buffer (per-layer transposes; lmWT if bigws)
    unsigned short* hbuf;   // LN output (bf16)
    unsigned short* ybuf;   // attn output (bf16)
    unsigned short* xfbuf;  // final-LN output (bf16)
    float*          bqkv;   // fused qkv biases (all layers)
    if (bigws) {
        wbuf  = (unsigned short*)(ws);                 // up to 62.5 MiB (lmWT at the end)
        hbuf  = (unsigned short*)(ws + (63ull << 20));
        ybuf  = (unsigned short*)(ws + (71ull << 20));
        xfbuf = (unsigned short*)(ws + (79ull << 20));
        bqkv  = (float*)(ws + (87ull << 20));
    } else {
        wbuf  = (unsigned short*)(ws);                 // 16 MiB
        hbuf  = (unsigned short*)(ws + (16u << 20));
        ybuf  = (unsigned short*)(ws + (24u << 20));
        xfbuf = (unsigned short*)(ws + (32u << 20));
        bqkv  = (float*)(ws + (40u << 20));
    }

    // scratch inside d_out (dead before final GEMMs overwrite all of d_out)
    float* outF = (float*)d_out;
    float* xbuf = outF;                                                        // 16 MiB residual fp32
    unsigned short* qkv = (unsigned short*)((char*)d_out + (16ull << 20));     // 24 MiB bf16 [4096][3072]
    unsigned short* hidden = (unsigned short*)((char*)d_out + (64ull << 20));  // 32 MiB bf16 [4096][4096]

    embed_kernel<<<MROWS, 256, 0, stream>>>(idx, tok, pos, xbuf);
    pack_qkv_bias<<<(NLAYER * 3072) / 256, 256, 0, stream>>>(bq, bk, bv, bqkv);

    for (int l = 0; l < NLAYER; l++) {
        const size_t wl = (size_t)l * DMODEL * DMODEL;
        ln_kernel<<<MROWS, 256, 0, stream>>>(xbuf, ln1g + l * DMODEL, ln1b + l * DMODEL, hbuf);

        transpose_qkv<<<dim3(16, 16, 3), 256, 0, stream>>>(Wq + wl, Wk + wl, Wv + wl, wbuf);
        gemm256<3><<<dim3((3072 / 256) * (MROWS / 256)), 512, 0, stream>>>(
            hbuf, wbuf, bqkv + l * 3072, nullptr, nullptr, qkv, MROWS, 3072, DMODEL, 3072);

        attn_kernel<<<MROWS * NHEAD / 4, 256, 0, stream>>>(qkv, ybuf);

        transpose_bf16<<<dim3(16, 16), 256, 0, stream>>>(Wo + wl, wbuf, DMODEL, DMODEL);
        gemm128<1><<<dim3((DMODEL / 128) * (MROWS / 128)), 512, 0, stream>>>(
            ybuf, wbuf, bo + l * DMODEL, xbuf, xbuf, nullptr, MROWS, DMODEL, DMODEL, DMODEL);

        ln_kernel<<<MROWS, 256, 0, stream>>>(xbuf, ln2g + l * DMODEL, ln2b + l * DMODEL, hbuf);

        transpose_bf16<<<dim3(FFN / 64, DMODEL / 64), 256, 0, stream>>>(W1 + (size_t)l * DMODEL * FFN, wbuf, DMODEL, FFN);
        gemm256<2><<<dim3((FFN / 256) * (MROWS / 256)), 512, 0, stream>>>(
            hbuf, wbuf, b1 + l * FFN, nullptr, nullptr, hidden, MROWS, FFN, DMODEL, FFN);

        transpose_bf16<<<dim3(DMODEL / 64, FFN / 64), 256, 0, stream>>>(W2 + (size_t)l * FFN * DMODEL, wbuf, FFN, DMODEL);
        gemm128<1><<<dim3((DMODEL / 128) * (MROWS / 128)), 512, 0, stream>>>(
            hidden, wbuf, b2 + l * DMODEL, xbuf, xbuf, nullptr, MROWS, DMODEL, FFN, DMODEL);
    }

    ln_kernel<<<MROWS, 256, 0, stream>>>(xbuf, lnfg, lnfb, xfbuf);

    if (bigws) {
        // single-shot LM head: transpose all of lmW, one GEMM (grid 2000)
        transpose_bf16<<<dim3(NVOCAB / 64, DMODEL / 64), 256, 0, stream>>>(lmW, wbuf, DMODEL, NVOCAB);
        gemm256<0><<<dim3((NVOCAB / 256) * (MROWS / 256)), 512, 0, stream>>>(
            xfbuf, wbuf, nullptr, nullptr, outF, nullptr, MROWS, NVOCAB, DMODEL, NVOCAB);
    } else {
        const int NCHUNK = 6400;
        for (int c = 0; c < NVOCAB / NCHUNK; c++) {
            int n0 = c * NCHUNK;
            transpose_bf16<<<dim3(NCHUNK / 64, DMODEL / 64), 256, 0, stream>>>(lmW + n0, wbuf, DMODEL, NVOCAB);
            gemm256<0><<<dim3((NCHUNK / 256) * (MROWS / 256)), 512, 0, stream>>>(
                xfbuf, wbuf, nullptr, nullptr, outF + n0, nullptr, MROWS, NCHUNK, DMODEL, NVOCAB);
        }
    }
}

// Round 5
// 1385.744 us; speedup vs baseline: 1.0734x; 1.0734x over previous
//
#include <hip/hip_runtime.h>
#include <cstdint>
#include <cstddef>

// ---------------- constants ----------------
#define MROWS   4096      // B*T
#define TSEQ    2048
#define DMODEL  1024
#define NHEAD   16
#define FFN     4096
#define NVOCAB  32000
#define NLAYER  4

typedef float  f32x4  __attribute__((ext_vector_type(4)));
typedef __bf16 bf16x8 __attribute__((ext_vector_type(8)));

__device__ __forceinline__ unsigned short f2bf(float f) {
    unsigned u = __builtin_bit_cast(unsigned, f);
    u += 0x7fffu + ((u >> 16) & 1u);
    return (unsigned short)(u >> 16);
}
__device__ __forceinline__ float bf2f(unsigned short u) {
    return __builtin_bit_cast(float, (unsigned)u << 16);
}

__device__ __forceinline__ float gelu_exact(float v) {
    return 0.5f * v * (1.0f + erff(v * 0.7071067811865476f));
}

// ---------------- embedding ----------------
__global__ __launch_bounds__(256) void embed_kernel(const int* __restrict__ idx,
                                                    const float* __restrict__ tok,
                                                    const float* __restrict__ pos,
                                                    float* __restrict__ x) {
    int row = blockIdx.x, tid = threadIdx.x;
    int token = idx[row];
    int t = row & (TSEQ - 1);
    float4 a = ((const float4*)(tok + (size_t)token * DMODEL))[tid];
    float4 p = ((const float4*)(pos + (size_t)t * DMODEL))[tid];
    a.x += p.x; a.y += p.y; a.z += p.z; a.w += p.w;
    ((float4*)(x + (size_t)row * DMODEL))[tid] = a;
}

// ---------------- LayerNorm fp32 in -> bf16 out ----------------
__global__ __launch_bounds__(256) void ln_kernel(const float* __restrict__ x,
                                                 const float* __restrict__ g,
                                                 const float* __restrict__ b,
                                                 unsigned short* __restrict__ out) {
    int row = blockIdx.x, tid = threadIdx.x;
    float4 v = ((const float4*)(x + (size_t)row * DMODEL))[tid];
    float s1 = v.x + v.y + v.z + v.w;
    float s2 = v.x * v.x + v.y * v.y + v.z * v.z + v.w * v.w;
    for (int s = 32; s; s >>= 1) { s1 += __shfl_xor(s1, s); s2 += __shfl_xor(s2, s); }
    __shared__ float red[8];
    int lane = tid & 63, w = tid >> 6;
    if (lane == 0) { red[w] = s1; red[4 + w] = s2; }
    __syncthreads();
    s1 = red[0] + red[1] + red[2] + red[3];
    s2 = red[4] + red[5] + red[6] + red[7];
    float mean = s1 * (1.0f / DMODEL);
    float var  = s2 * (1.0f / DMODEL) - mean * mean;
    float rs   = rsqrtf(var + 1e-5f);
    float4 gv = ((const float4*)g)[tid];
    float4 bv = ((const float4*)b)[tid];
    size_t o = (size_t)row * DMODEL + tid * 4;
    out[o + 0] = f2bf((v.x - mean) * rs * gv.x + bv.x);
    out[o + 1] = f2bf((v.y - mean) * rs * gv.y + bv.y);
    out[o + 2] = f2bf((v.z - mean) * rs * gv.z + bv.z);
    out[o + 3] = f2bf((v.w - mean) * rs * gv.w + bv.w);
}

// ---------------- fast transpose + fp32->bf16: W[K][N](ldW) -> WT[N][K] ----------------
__global__ __launch_bounds__(256) void transpose_bf16(const float* __restrict__ W,
                                                      unsigned short* __restrict__ WT,
                                                      int K, int ldW) {
    __shared__ float tile[64][65];
    int n0 = blockIdx.x * 64, k0 = blockIdx.y * 64;
    int tid = threadIdx.x;
    int lr4 = tid & 15;
    int rw  = tid >> 4;
#pragma unroll
    for (int p = 0; p < 4; ++p) {
        int k = rw + p * 16;
        float4 v = *(const float4*)(W + (size_t)(k0 + k) * ldW + n0 + lr4 * 4);
        tile[k][lr4 * 4 + 0] = v.x;
        tile[k][lr4 * 4 + 1] = v.y;
        tile[k][lr4 * 4 + 2] = v.z;
        tile[k][lr4 * 4 + 3] = v.w;
    }
    __syncthreads();
    int kc = tid & 15;
    int nr = tid >> 4;
#pragma unroll
    for (int p = 0; p < 4; ++p) {
        int n = nr + p * 16;
        ushort4 o;
        o.x = f2bf(tile[kc * 4 + 0][n]);
        o.y = f2bf(tile[kc * 4 + 1][n]);
        o.z = f2bf(tile[kc * 4 + 2][n]);
        o.w = f2bf(tile[kc * 4 + 3][n]);
        *(ushort4*)(WT + (size_t)(n0 + n) * K + k0 + kc * 4) = o;
    }
}

// fused QKV transpose: z selects Wq/Wk/Wv, writes into 3-stacked WT
__global__ __launch_bounds__(256) void transpose_qkv(const float* __restrict__ Wq,
                                                     const float* __restrict__ Wk,
                                                     const float* __restrict__ Wv,
                                                     unsigned short* __restrict__ WT) {
    __shared__ float tile[64][65];
    const float* W = (blockIdx.z == 0) ? Wq : (blockIdx.z == 1) ? Wk : Wv;
    unsigned short* dst = WT + (size_t)blockIdx.z * DMODEL * DMODEL;
    int n0 = blockIdx.x * 64, k0 = blockIdx.y * 64;
    int tid = threadIdx.x;
    int lr4 = tid & 15, rw = tid >> 4;
#pragma unroll
    for (int p = 0; p < 4; ++p) {
        int k = rw + p * 16;
        float4 v = *(const float4*)(W + (size_t)(k0 + k) * DMODEL + n0 + lr4 * 4);
        tile[k][lr4 * 4 + 0] = v.x;
        tile[k][lr4 * 4 + 1] = v.y;
        tile[k][lr4 * 4 + 2] = v.z;
        tile[k][lr4 * 4 + 3] = v.w;
    }
    __syncthreads();
    int kc = tid & 15, nr = tid >> 4;
#pragma unroll
    for (int p = 0; p < 4; ++p) {
        int n = nr + p * 16;
        ushort4 o;
        o.x = f2bf(tile[kc * 4 + 0][n]);
        o.y = f2bf(tile[kc * 4 + 1][n]);
        o.z = f2bf(tile[kc * 4 + 2][n]);
        o.w = f2bf(tile[kc * 4 + 3][n]);
        *(ushort4*)(dst + (size_t)(n0 + n) * DMODEL + k0 + kc * 4) = o;
    }
}

// ---------------- pack fused QKV bias for all layers ----------------
__global__ __launch_bounds__(256) void pack_qkv_bias(const float* __restrict__ bq,
                                                     const float* __restrict__ bk,
                                                     const float* __restrict__ bv,
                                                     float* __restrict__ dst) {
    int i = blockIdx.x * 256 + threadIdx.x;
    int l = i / 3072, c = i % 3072;
    float v = (c < 1024) ? bq[l * 1024 + c]
            : (c < 2048) ? bk[l * 1024 + c - 1024]
                         : bv[l * 1024 + c - 2048];
    dst[i] = v;
}

// ---------------- band attention (width-3), bf16 qkv in ----------------
__global__ __launch_bounds__(256) void attn_kernel(const unsigned short* __restrict__ qkv,
                                                   unsigned short* __restrict__ y) {
    int wid  = (blockIdx.x * 256 + threadIdx.x) >> 6;
    int lane = threadIdx.x & 63;
    int h = wid & (NHEAD - 1);
    int row = wid >> 4;
    int t = row & (TSEQ - 1);
    const unsigned short* base = qkv + (size_t)row * 3072 + h * 64;
    float qd = bf2f(base[lane]);
    float d0 = qd * bf2f(base[1024 + lane]);
    float d1 = (t >= 1) ? qd * bf2f(base[1024 - 3072 + lane]) : 0.0f;
    float d2 = (t >= 2) ? qd * bf2f(base[1024 - 6144 + lane]) : 0.0f;
    for (int s = 32; s; s >>= 1) {
        d0 += __shfl_xor(d0, s); d1 += __shfl_xor(d1, s); d2 += __shfl_xor(d2, s);
    }
    d0 *= 0.125f; d1 *= 0.125f; d2 *= 0.125f;
    float m = d0;
    if (t >= 1) m = fmaxf(m, d1);
    if (t >= 2) m = fmaxf(m, d2);
    float p0 = expf(d0 - m);
    float p1 = (t >= 1) ? expf(d1 - m) : 0.0f;
    float p2 = (t >= 2) ? expf(d2 - m) : 0.0f;
    float den = p0 + p1 + p2;
    float v0 = bf2f(base[2048 + lane]);
    float v1 = (t >= 1) ? bf2f(base[2048 - 3072 + lane]) : 0.0f;
    float v2 = (t >= 2) ? bf2f(base[2048 - 6144 + lane]) : 0.0f;
    float yv = (p0 * v0 + p1 * v1 + p2 * v2) / den;
    y[(size_t)row * DMODEL + h * 64 + lane] = f2bf(yv);
}

// ======================================================================
// 256x256x64 GEMM, 8 waves, software-pipelined 4-phase schedule.
// Every phase's MFMA consumes fragments ds_read one phase EARLIER, so LDS
// latency hides under the in-flight MFMA cluster (m196 lever). Counted
// vmcnt(2) at P1/P3 only; never drained mid-loop (vmcnt(0) only on the
// last tile's P1). All reads sit >=1 barrier after their covering vmcnt.
// LDS swizzle: per-region 8-slot scheme (measured 0 bank conflicts in R4).
// ======================================================================
__device__ __forceinline__ void stage_kh(const unsigned short* __restrict__ g,
                                         unsigned short* region, int K, int kh, int tid) {
#pragma unroll
    for (int i = 0; i < 2; ++i) {
        int pc = i * 512 + tid;
        int line = pc >> 3, slot = pc & 7;
        int r  = line * 2 + (slot >> 2);
        int cl = (slot & 3) ^ (line & 3);
        __builtin_amdgcn_global_load_lds(
            (const __attribute__((address_space(1))) void*)(g + (size_t)r * K + kh * 32 + cl * 8),
            (__attribute__((address_space(3))) void*)(region + (size_t)pc * 8), 16, 0, 0);
    }
}

template <int EPI>
__global__ __launch_bounds__(512, 2) void gemm256(const unsigned short* __restrict__ A,
                                                  const unsigned short* __restrict__ BT,
                                                  const float* __restrict__ bias,
                                                  const float* __restrict__ res,
                                                  float* __restrict__ outF,
                                                  unsigned short* __restrict__ outB,
                                                  int M, int N, int K, int ldc) {
    __shared__ unsigned short As[2][2][8192];   // [buf][kh][region]
    __shared__ unsigned short Bs[2][2][8192];
    const int tid = threadIdx.x;
    const int lane = tid & 63, wid = tid >> 6;
    const int wr = wid >> 2, wc = wid & 3;       // 2 x 4 waves; wave tile 128x64
    const int lr = lane & 15, kq = lane >> 4;

    // bijective XCD swizzle (m204)
    const int nbn = N >> 8;
    const int nwg = gridDim.x;
    int orig = blockIdx.x;
    int q8 = nwg >> 3, r8 = nwg & 7;
    int xcd = orig & 7, lin = orig >> 3;
    int wg = (xcd < r8 ? xcd * (q8 + 1) : r8 * (q8 + 1) + (xcd - r8) * q8) + lin;
    int bm = wg / nbn, bn = wg % nbn;

    const unsigned short* Ab = A + (size_t)bm * 256 * K;
    const unsigned short* Bb = BT + (size_t)bn * 256 * K;

    // per-lane LDS read offset (ushort units) within a kh-region
    const int slot = ((lane & 1) << 2) | (kq ^ ((lr >> 1) & 3));
    const int laneOff = ((lr >> 1) << 6) + slot * 8;
    const int aOff = wr * 4096 + laneOff;
    const int bOff = wc * 2048 + laneOff;

    f32x4 acc[8][4] = {};
    const int nt = K >> 6;

    // prologue: tile 0 stages, order A0,B0,A1,B1 (= steady-state order)
    stage_kh(Ab, &As[0][0][0], K, 0, tid);
    stage_kh(Bb, &Bs[0][0][0], K, 0, tid);
    stage_kh(Ab, &As[0][1][0], K, 1, tid);
    stage_kh(Bb, &Bs[0][1][0], K, 1, tid);

    bf16x8 bk0[4], alo0[4];
    asm volatile("s_waitcnt vmcnt(4)" ::: "memory");   // A0,B0 landed (all waves after barrier)
    __builtin_amdgcn_s_barrier();
#pragma unroll
    for (int n = 0; n < 4; ++n) bk0[n] = *(const bf16x8*)(&Bs[0][0][0] + bOff + n * 512);
#pragma unroll
    for (int j = 0; j < 4; ++j) alo0[j] = *(const bf16x8*)(&As[0][0][0] + aOff + j * 512);

    for (int t = 0; t < nt; ++t) {
        const int buf = t & 1;
        const bool pf = (t + 1) < nt;
        const unsigned short* rA0 = &As[buf][0][0];
        const unsigned short* rB1 = &Bs[buf][1][0];
        const unsigned short* rA1 = &As[buf][1][0];
        const unsigned short* gA = Ab + (size_t)(t + 1) * 64;
        const unsigned short* gB = Bb + (size_t)(t + 1) * 64;

        // ---- P0: MFMA (kh0, rows 0..63); read ahi0; stage A'(kh0) ----
        bf16x8 ahi0[4];
#pragma unroll
        for (int j = 0; j < 4; ++j) ahi0[j] = *(const bf16x8*)(rA0 + aOff + (4 + j) * 512);
        if (pf) stage_kh(gA, &As[buf ^ 1][0][0], K, 0, tid);
        __builtin_amdgcn_s_barrier();
        __builtin_amdgcn_s_setprio(1);
#pragma unroll
        for (int j = 0; j < 4; ++j)
#pragma unroll
            for (int n = 0; n < 4; ++n)
                acc[j][n] = __builtin_amdgcn_mfma_f32_16x16x32_bf16(alo0[j], bk0[n], acc[j][n], 0, 0, 0);
        __builtin_amdgcn_s_setprio(0);

        // ---- P1: vmcnt lands (A-kh1,B-kh1); read bk1, alo1; stage B'(kh0);
        //          MFMA (kh0, rows 64..127) ----
        if (pf) asm volatile("s_waitcnt vmcnt(2)" ::: "memory");
        else    asm volatile("s_waitcnt vmcnt(0)" ::: "memory");
        __builtin_amdgcn_s_barrier();
        bf16x8 bk1[4], alo1[4];
#pragma unroll
        for (int n = 0; n < 4; ++n) bk1[n] = *(const bf16x8*)(rB1 + bOff + n * 512);
#pragma unroll
        for (int j = 0; j < 4; ++j) alo1[j] = *(const bf16x8*)(rA1 + aOff + j * 512);
        if (pf) stage_kh(gB, &Bs[buf ^ 1][0][0], K, 0, tid);
        __builtin_amdgcn_s_barrier();
        __builtin_amdgcn_s_setprio(1);
#pragma unroll
        for (int j = 0; j < 4; ++j)
#pragma unroll
            for (int n = 0; n < 4; ++n)
                acc[4 + j][n] = __builtin_amdgcn_mfma_f32_16x16x32_bf16(ahi0[j], bk0[n], acc[4 + j][n], 0, 0, 0);
        __builtin_amdgcn_s_setprio(0);

        // ---- P2: read ahi1; stage A'(kh1); MFMA (kh1, rows 0..63) ----
        bf16x8 ahi1[4];
#pragma unroll
        for (int j = 0; j < 4; ++j) ahi1[j] = *(const bf16x8*)(rA1 + aOff + (4 + j) * 512);
        if (pf) stage_kh(gA, &As[buf ^ 1][1][0], K, 1, tid);
        __builtin_amdgcn_s_barrier();
        __builtin_amdgcn_s_setprio(1);
#pragma unroll
        for (int j = 0; j < 4; ++j)
#pragma unroll
            for (int n = 0; n < 4; ++n)
                acc[j][n] = __builtin_amdgcn_mfma_f32_16x16x32_bf16(alo1[j], bk1[n], acc[j][n], 0, 0, 0);
        __builtin_amdgcn_s_setprio(0);

        // ---- P3: vmcnt lands (A'(kh0),B'(kh0)); read next tile's bk0, alo0;
        //          stage B'(kh1); MFMA (kh1, rows 64..127) ----
        if (pf) {
            asm volatile("s_waitcnt vmcnt(2)" ::: "memory");
            __builtin_amdgcn_s_barrier();
            const unsigned short* nA0 = &As[buf ^ 1][0][0];
            const unsigned short* nB0 = &Bs[buf ^ 1][0][0];
#pragma unroll
            for (int n = 0; n < 4; ++n) bk0[n] = *(const bf16x8*)(nB0 + bOff + n * 512);
#pragma unroll
            for (int j = 0; j < 4; ++j) alo0[j] = *(const bf16x8*)(nA0 + aOff + j * 512);
            stage_kh(gB, &Bs[buf ^ 1][1][0], K, 1, tid);
        }
        __builtin_amdgcn_s_barrier();
        __builtin_amdgcn_s_setprio(1);
#pragma unroll
        for (int j = 0; j < 4; ++j)
#pragma unroll
            for (int n = 0; n < 4; ++n)
                acc[4 + j][n] = __builtin_amdgcn_mfma_f32_16x16x32_bf16(ahi1[j], bk1[n], acc[4 + j][n], 0, 0, 0);
        __builtin_amdgcn_s_setprio(0);
    }

    // epilogue
    const int row0 = bm * 256 + wr * 128;
    const int col0 = bn * 256 + wc * 64;
#pragma unroll
    for (int m = 0; m < 8; ++m) {
#pragma unroll
        for (int n = 0; n < 4; ++n) {
            int col = col0 + n * 16 + lr;
            int rbase = row0 + m * 16 + kq * 4;
            float bb = bias ? bias[col] : 0.0f;
#pragma unroll
            for (int j = 0; j < 4; ++j) {
                size_t off = (size_t)(rbase + j) * ldc + col;
                float v = acc[m][n][j] + bb;
                if (EPI == 1) v += res[off];
                if (EPI == 2)      outB[off] = f2bf(gelu_exact(v));
                else if (EPI == 3) outB[off] = f2bf(v);
                else               outF[off] = v;
            }
        }
    }
}

// ======================================================================
// 128x128x64, 8-wave, TRIPLE-buffered counted-vmcnt GEMM (for N=1024)
// ======================================================================
__device__ __forceinline__ void stage128(const unsigned short* __restrict__ g,
                                         unsigned short* s, int K, int tid) {
#pragma unroll
    for (int i = 0; i < 2; ++i) {
        int t2 = tid + i * 512;
        int row = t2 >> 3;
        int col = ((t2 & 7) ^ (row & 7)) * 8;
        __builtin_amdgcn_global_load_lds(
            (const __attribute__((address_space(1))) void*)(g + (size_t)row * K + col),
            (__attribute__((address_space(3))) void*)(s + (size_t)t2 * 8), 16, 0, 0);
    }
}

template <int EPI>
__global__ __launch_bounds__(512, 2) void gemm128(const unsigned short* __restrict__ A,
                                                  const unsigned short* __restrict__ BT,
                                                  const float* __restrict__ bias,
                                                  const float* __restrict__ res,
                                                  float* __restrict__ outF,
                                                  unsigned short* __restrict__ outB,
                                                  int M, int N, int K, int ldc) {
    __shared__ unsigned short As[3][128 * 64];
    __shared__ unsigned short Bs[3][128 * 64];
    const int tid = threadIdx.x;
    const int lane = tid & 63, wid = tid >> 6;
    const int wr = wid >> 2, wc = wid & 3;
    const int lr = lane & 15, kq = lane >> 4;

    const int nbn = N >> 7;
    const int nwg = gridDim.x;
    int orig = blockIdx.x;
    int q8 = nwg >> 3, r8 = nwg & 7;
    int xcd = orig & 7, lin = orig >> 3;
    int wg = (xcd < r8 ? xcd * (q8 + 1) : r8 * (q8 + 1) + (xcd - r8) * q8) + lin;
    int bm = wg / nbn, bn = wg % nbn;

    const unsigned short* Ab = A + (size_t)bm * 128 * K;
    const unsigned short* Bb = BT + (size_t)bn * 128 * K;

    const int aBase = (wr * 64 + lr) * 64;
    const int bBase = (wc * 32 + lr) * 64;
    const int c0 = (kq ^ (lr & 7)) * 8;
    const int c1 = ((4 + kq) ^ (lr & 7)) * 8;

    f32x4 acc[4][2] = {};
    const int nt = K >> 6;

    stage128(Ab,      &As[0][0], K, tid);
    stage128(Bb,      &Bs[0][0], K, tid);
    stage128(Ab + 64, &As[1][0], K, tid);
    stage128(Bb + 64, &Bs[1][0], K, tid);
    asm volatile("s_waitcnt vmcnt(4)" ::: "memory");
    __builtin_amdgcn_s_barrier();

    for (int t = 0; t < nt; ++t) {
        const unsigned short* sA = &As[t % 3][0];
        const unsigned short* sB = &Bs[t % 3][0];
        const bool pf = (t + 2) < nt;
        unsigned short* dA = &As[(t + 2) % 3][0];
        unsigned short* dB = &Bs[(t + 2) % 3][0];
        const unsigned short* gA = Ab + (size_t)(t + 2) * 64;
        const unsigned short* gB = Bb + (size_t)(t + 2) * 64;

        bf16x8 bfr[2][2];
#pragma unroll
        for (int n = 0; n < 2; ++n) {
            bfr[n][0] = *reinterpret_cast<const bf16x8*>(sB + bBase + n * 16 * 64 + c0);
            bfr[n][1] = *reinterpret_cast<const bf16x8*>(sB + bBase + n * 16 * 64 + c1);
        }
#pragma unroll
        for (int p = 0; p < 2; ++p) {
            bf16x8 af[2][2];
#pragma unroll
            for (int jm = 0; jm < 2; ++jm) {
                const int ro = aBase + ((p * 2 + jm) * 16) * 64;
                af[jm][0] = *reinterpret_cast<const bf16x8*>(sA + ro + c0);
                af[jm][1] = *reinterpret_cast<const bf16x8*>(sA + ro + c1);
            }
            if (pf && p == 0) stage128(gA, dA, K, tid);
            if (pf && p == 1) stage128(gB, dB, K, tid);
            __builtin_amdgcn_s_barrier();
            __builtin_amdgcn_s_setprio(1);
#pragma unroll
            for (int jm = 0; jm < 2; ++jm)
#pragma unroll
                for (int n = 0; n < 2; ++n) {
                    acc[p * 2 + jm][n] = __builtin_amdgcn_mfma_f32_16x16x32_bf16(af[jm][0], bfr[n][0], acc[p * 2 + jm][n], 0, 0, 0);
                    acc[p * 2 + jm][n] = __builtin_amdgcn_mfma_f32_16x16x32_bf16(af[jm][1], bfr[n][1], acc[p * 2 + jm][n], 0, 0, 0);
                }
            __builtin_amdgcn_s_setprio(0);
        }
        if (t + 1 < nt) {
            if (pf) asm volatile("s_waitcnt vmcnt(4)" ::: "memory");
            else    asm volatile("s_waitcnt vmcnt(0)" ::: "memory");
            __builtin_amdgcn_s_barrier();
        }
    }

    const int row0 = bm * 128 + wr * 64;
    const int col0 = bn * 128 + wc * 32;
#pragma unroll
    for (int m = 0; m < 4; ++m) {
#pragma unroll
        for (int n = 0; n < 2; ++n) {
            int col = col0 + n * 16 + lr;
            int rbase = row0 + m * 16 + kq * 4;
            float bb = bias ? bias[col] : 0.0f;
#pragma unroll
            for (int j = 0; j < 4; ++j) {
                size_t off = (size_t)(rbase + j) * ldc + col;
                float v = acc[m][n][j] + bb;
                if (EPI == 1) v += res[off];
                if (EPI == 2)      outB[off] = f2bf(gelu_exact(v));
                else if (EPI == 3) outB[off] = f2bf(v);
                else               outF[off] = v;
            }
        }
    }
}

// ---------------- host launch ----------------
extern "C" void kernel_launch(void* const* d_in, const int* in_sizes, int n_in,
                              void* d_out, int out_size, void* d_ws, size_t ws_size,
                              hipStream_t stream) {
    const int*   idx  = (const int*)d_in[0];
    const float* tok  = (const float*)d_in[1];
    const float* pos  = (const float*)d_in[2];
    const float* Wq   = (const float*)d_in[3];
    const float* bq   = (const float*)d_in[4];
    const float* Wk   = (const float*)d_in[5];
    const float* bk   = (const float*)d_in[6];
    const float* Wv   = (const float*)d_in[7];
    const float* bv   = (const float*)d_in[8];
    const float* Wo   = (const float*)d_in[9];
    const float* bo   = (const float*)d_in[10];
    const float* ln1g = (const float*)d_in[11];
    const float* ln1b = (const float*)d_in[12];
    const float* W1   = (const float*)d_in[13];
    const float* b1   = (const float*)d_in[14];
    const float* W2   = (const float*)d_in[15];
    const float* b2   = (const float*)d_in[16];
    const float* ln2g = (const float*)d_in[17];
    const float* ln2b = (const float*)d_in[18];
    const float* lnfg = (const float*)d_in[19];
    const float* lnfb = (const float*)d_in[20];
    const float* lmW  = (const float*)d_in[21];

    const bool bigws = ws_size >= (92ull << 20);

    char* ws = (char*)d_ws;
    unsigned short* wbuf;
    unsigned short* hbuf;
    unsigned short* ybuf;
    unsigned short* xfbuf;
    float*          bqkv;
    if (bigws) {
        wbuf  = (unsigned short*)(ws);
        hbuf  = (unsigned short*)(ws + (63ull << 20));
        ybuf  = (unsigned short*)(ws + (71ull << 20));
        xfbuf = (unsigned short*)(ws + (79ull << 20));
        bqkv  = (float*)(ws + (87ull << 20));
    } else {
        wbuf  = (unsigned short*)(ws);
        hbuf  = (unsigned short*)(ws + (16u << 20));
        ybuf  = (unsigned short*)(ws + (24u << 20));
        xfbuf = (unsigned short*)(ws + (32u << 20));
        bqkv  = (float*)(ws + (40u << 20));
    }

    // scratch inside d_out (dead before final GEMMs overwrite all of d_out)
    float* outF = (float*)d_out;
    float* xbuf = outF;                                                        // 16 MiB residual fp32
    unsigned short* qkv = (unsigned short*)((char*)d_out + (16ull << 20));     // 24 MiB bf16 [4096][3072]
    unsigned short* hidden = (unsigned short*)((char*)d_out + (64ull << 20));  // 32 MiB bf16 [4096][4096]

    embed_kernel<<<MROWS, 256, 0, stream>>>(idx, tok, pos, xbuf);
    pack_qkv_bias<<<(NLAYER * 3072) / 256, 256, 0, stream>>>(bq, bk, bv, bqkv);

    for (int l = 0; l < NLAYER; l++) {
        const size_t wl = (size_t)l * DMODEL * DMODEL;
        ln_kernel<<<MROWS, 256, 0, stream>>>(xbuf, ln1g + l * DMODEL, ln1b + l * DMODEL, hbuf);

        transpose_qkv<<<dim3(16, 16, 3), 256, 0, stream>>>(Wq + wl, Wk + wl, Wv + wl, wbuf);
        gemm256<3><<<dim3((3072 / 256) * (MROWS / 256)), 512, 0, stream>>>(
            hbuf, wbuf, bqkv + l * 3072, nullptr, nullptr, qkv, MROWS, 3072, DMODEL, 3072);

        attn_kernel<<<MROWS * NHEAD / 4, 256, 0, stream>>>(qkv, ybuf);

        transpose_bf16<<<dim3(16, 16), 256, 0, stream>>>(Wo + wl, wbuf, DMODEL, DMODEL);
        gemm128<1><<<dim3((DMODEL / 128) * (MROWS / 128)), 512, 0, stream>>>(
            ybuf, wbuf, bo + l * DMODEL, xbuf, xbuf, nullptr, MROWS, DMODEL, DMODEL, DMODEL);

        ln_kernel<<<MROWS, 256, 0, stream>>>(xbuf, ln2g + l * DMODEL, ln2b + l * DMODEL, hbuf);

        transpose_bf16<<<dim3(FFN / 64, DMODEL / 64), 256, 0, stream>>>(W1 + (size_t)l * DMODEL * FFN, wbuf, DMODEL, FFN);
        gemm256<2><<<dim3((FFN / 256) * (MROWS / 256)), 512, 0, stream>>>(
            hbuf, wbuf, b1 + l * FFN, nullptr, nullptr, hidden, MROWS, FFN, DMODEL, FFN);

        transpose_bf16<<<dim3(DMODEL / 64, FFN / 64), 256, 0, stream>>>(W2 + (size_t)l * FFN * DMODEL, wbuf, FFN, DMODEL);
        gemm128<1><<<dim3((DMODEL / 128) * (MROWS / 128)), 512, 0, stream>>>(
            hidden, wbuf, b2 + l * DMODEL, xbuf, xbuf, nullptr, MROWS, DMODEL, FFN, DMODEL);
    }

    ln_kernel<<<MROWS, 256, 0, stream>>>(xbuf, lnfg, lnfb, xfbuf);

    if (bigws) {
        transpose_bf16<<<dim3(NVOCAB / 64, DMODEL / 64), 256, 0, stream>>>(lmW, wbuf, DMODEL, NVOCAB);
        gemm256<0><<<dim3((NVOCAB / 256) * (MROWS / 256)), 512, 0, stream>>>(
            xfbuf, wbuf, nullptr, nullptr, outF, nullptr, MROWS, NVOCAB, DMODEL, NVOCAB);
    } else {
        const int NCHUNK = 6400;
        for (int c = 0; c < NVOCAB / NCHUNK; c++) {
            int n0 = c * NCHUNK;
            transpose_bf16<<<dim3(NCHUNK / 64, DMODEL / 64), 256, 0, stream>>>(lmW + n0, wbuf, DMODEL, NVOCAB);
            gemm256<0><<<dim3((NCHUNK / 256) * (MROWS / 256)), 512, 0, stream>>>(
                xfbuf, wbuf, nullptr, nullptr, outF + n0, nullptr, MROWS, NCHUNK, DMODEL, NVOCAB);
        }
    }
}